// Round 1
// baseline (255.099 us; speedup 1.0000x reference)
//
#include <hip/hip_runtime.h>

#define NB 2
#define CIN 256
#define HH 64
#define WW 64
#define CCMP 64
#define HO 128
#define WO 128

// ---------------- k1: 1x1 conv x(2,256,64,64) -> comp(2,64,64,64) ----------------
__global__ void k1_comp(const float* __restrict__ x, const float* __restrict__ wc,
                        const float* __restrict__ bc, float* __restrict__ comp) {
  int b = blockIdx.x;          // 256 blocks: n(2) * ccg(8) * hq(16)
  int n = b >> 7;
  int ccg = (b >> 4) & 7;
  int hq = b & 15;
  int hsub = threadIdx.x >> 6;
  int w = threadIdx.x & 63;
  int h = hq * 4 + hsub;
  float acc[8];
#pragma unroll
  for (int j = 0; j < 8; ++j) acc[j] = bc[ccg * 8 + j];
  const float* xp = x + ((size_t)(n * CIN) * HH + h) * WW + w;
#pragma unroll 4
  for (int c = 0; c < CIN; ++c) {
    float xv = xp[(size_t)c * HH * WW];
#pragma unroll
    for (int j = 0; j < 8; ++j) acc[j] += xv * wc[(ccg * 8 + j) * CIN + c];
  }
#pragma unroll
  for (int j = 0; j < 8; ++j)
    comp[((size_t)(n * CCMP + ccg * 8 + j) * HH + h) * WW + w] = acc[j];
}

// ------------- k2: fused 3x3 convs comp -> off(8ch) + ker(25ch), pad 1 -------------
__global__ void k2_conv3(const float* __restrict__ comp,
                         const float* __restrict__ w_off, const float* __restrict__ b_off,
                         const float* __restrict__ w_ker, const float* __restrict__ b_ker,
                         float* __restrict__ offb, float* __restrict__ kerb) {
  int b = blockIdx.x;           // 352 blocks: n(2) * ocg(11) * hq(16)
  int n = b / 176;
  int r = b % 176;
  int ocg = r / 16;
  int hq = r % 16;
  int hsub = threadIdx.x >> 6;
  int w = threadIdx.x & 63;
  int h = hq * 4 + hsub;
  float acc[3];
#pragma unroll
  for (int j = 0; j < 3; ++j) {
    int oc = ocg * 3 + j;
    acc[j] = (oc < 8) ? b_off[oc] : b_ker[oc - 8];
  }
  for (int c = 0; c < CCMP; ++c) {
    const float* cp = comp + (size_t)(n * CCMP + c) * HH * WW;
    float t[9];
#pragma unroll
    for (int dy = 0; dy < 3; ++dy) {
      int rr = h + dy - 1;
#pragma unroll
      for (int dx = 0; dx < 3; ++dx) {
        int cc = w + dx - 1;
        bool ok = (rr >= 0) && (rr < HH) && (cc >= 0) && (cc < WW);
        t[dy * 3 + dx] = ok ? cp[rr * WW + cc] : 0.f;
      }
    }
#pragma unroll
    for (int j = 0; j < 3; ++j) {
      int oc = ocg * 3 + j;
      const float* wp = (oc < 8) ? (w_off + (size_t)(oc * CCMP + c) * 9)
                                 : (w_ker + (size_t)((oc - 8) * CCMP + c) * 9);
#pragma unroll
      for (int t9 = 0; t9 < 9; ++t9) acc[j] += t[t9] * wp[t9];
    }
  }
#pragma unroll
  for (int j = 0; j < 3; ++j) {
    int oc = ocg * 3 + j;
    if (oc < 8) offb[((size_t)(n * 8 + oc) * HH + h) * WW + w] = acc[j];
    else        kerb[((size_t)(n * 25 + (oc - 8)) * HH + h) * WW + w] = acc[j];
  }
}

// ---------------- k3: softmax over the 25 ker channels, in place ----------------
__global__ void k3_softmax(float* __restrict__ kerb) {
  int t = blockIdx.x * 256 + threadIdx.x;  // 8192 threads
  int n = t >> 12;
  int pos = t & 4095;
  float v[25];
  float mx = -1e30f;
#pragma unroll
  for (int k = 0; k < 25; ++k) {
    v[k] = kerb[(size_t)(n * 25 + k) * 4096 + pos];
    mx = fmaxf(mx, v[k]);
  }
  float s = 0.f;
#pragma unroll
  for (int k = 0; k < 25; ++k) { v[k] = expf(v[k] - mx); s += v[k]; }
  float inv = 1.f / s;
#pragma unroll
  for (int k = 0; k < 25; ++k) kerb[(size_t)(n * 25 + k) * 4096 + pos] = v[k] * inv;
}

// ------- k4: bilinear-sample mask at offset positions -> wts(n,h,w,[pq],[k]) -------
__global__ void k4_wts(const float* __restrict__ offb, const float* __restrict__ mask,
                       float* __restrict__ wts) {
  int t = blockIdx.x * 256 + threadIdx.x;   // 32768 threads: (n, ho, wo)
  int n = t >> 14;
  int r = t & 16383;
  int ho = r >> 7;
  int wo = r & 127;
  int h = ho >> 1, p = ho & 1, w = wo >> 1, q = wo & 1;
  int pq = p * 2 + q;
  float offx = offb[((size_t)(n * 8 + pq) * HH + h) * WW + w];
  float offy = offb[((size_t)(n * 8 + 4 + pq) * HH + h) * WW + w];
  // align_corners=True + border clamp algebra reduces to sampling at (h+offy, w+offx)
  float ix = fminf(fmaxf((float)w + offx, 0.f), 63.f);
  float iy = fminf(fmaxf((float)h + offy, 0.f), 63.f);
  float x0f = floorf(ix), y0f = floorf(iy);
  float fx = ix - x0f, fy = iy - y0f;
  int x0 = (int)x0f, y0 = (int)y0f;
  int x1 = min(x0 + 1, 63), y1 = min(y0 + 1, 63);
  float w00 = (1.f - fx) * (1.f - fy), w01 = fx * (1.f - fy);
  float w10 = (1.f - fx) * fy,         w11 = fx * fy;
  float* wp = wts + ((((size_t)n * HH + h) * WW + w) * 4 + pq) * 25;
#pragma unroll
  for (int k = 0; k < 25; ++k) {
    const float* mp = mask + (size_t)(n * 25 + k) * 4096;
    wp[k] = mp[y0 * 64 + x0] * w00 + mp[y0 * 64 + x1] * w01 +
            mp[y1 * 64 + x0] * w10 + mp[y1 * 64 + x1] * w11;
  }
}

// -------- k5: out[n,c,2h+p,2w+q] = sum_k wt[n,h,w,pq,k] * x[n,c,h+ki-2,w+kj-2] --------
__global__ void k5_out(const float* __restrict__ x, const float* __restrict__ wts,
                       float* __restrict__ out) {
  int b = blockIdx.x;       // 256 blocks: n(2) * h(64) * wseg(2)
  int n = b >> 7;
  int r = b & 127;
  int h = r >> 1;
  int wseg = r & 1;
  int c = threadIdx.x;
  const float* xc = x + (size_t)(n * CIN + c) * HH * WW;
  int w0 = wseg * 32;
  for (int w = w0; w < w0 + 32; ++w) {
    const float* wp = wts + (((size_t)n * HH + h) * WW + w) * 100;  // uniform -> s_load
    float a0 = 0.f, a1 = 0.f, a2 = 0.f, a3 = 0.f;
#pragma unroll
    for (int dy = 0; dy < 5; ++dy) {
      int rr = h + dy - 2;
      bool rok = (rr >= 0) && (rr < HH);
#pragma unroll
      for (int dx = 0; dx < 5; ++dx) {
        int cc = w + dx - 2;
        bool ok = rok && (cc >= 0) && (cc < WW);
        float xv = ok ? xc[rr * WW + cc] : 0.f;
        int k = dy * 5 + dx;
        a0 += wp[k] * xv;
        a1 += wp[25 + k] * xv;
        a2 += wp[50 + k] * xv;
        a3 += wp[75 + k] * xv;
      }
    }
    float* o0 = out + ((size_t)(n * CIN + c) * HO + 2 * h) * WO + 2 * w;
    float* o1 = o0 + WO;
    o0[0] = a0; o0[1] = a1;
    o1[0] = a2; o1[1] = a3;
  }
}

extern "C" void kernel_launch(void* const* d_in, const int* in_sizes, int n_in,
                              void* d_out, int out_size, void* d_ws, size_t ws_size,
                              hipStream_t stream) {
  const float* x      = (const float*)d_in[0];
  const float* w_comp = (const float*)d_in[1];
  const float* b_comp = (const float*)d_in[2];
  const float* w_off  = (const float*)d_in[3];
  const float* b_off  = (const float*)d_in[4];
  const float* w_ker  = (const float*)d_in[5];
  const float* b_ker  = (const float*)d_in[6];
  float* out = (float*)d_out;

  float* ws   = (float*)d_ws;
  float* comp = ws;                       // 2*64*64*64   = 524288 floats
  float* offb = comp + 524288;            // 2*8*64*64    = 65536
  float* kerb = offb + 65536;             // 2*25*64*64   = 204800 (softmax in place)
  float* wts  = kerb + 204800;            // 2*64*64*100  = 819200

  k1_comp<<<256, 256, 0, stream>>>(x, w_comp, b_comp, comp);
  k2_conv3<<<352, 256, 0, stream>>>(comp, w_off, b_off, w_ker, b_ker, offb, kerb);
  k3_softmax<<<32, 256, 0, stream>>>(kerb);
  k4_wts<<<128, 256, 0, stream>>>(offb, kerb, wts);
  k5_out<<<256, 256, 0, stream>>>(x, wts, out);
}

// Round 3
// 111.176 us; speedup vs baseline: 2.2946x; 2.2946x over previous
//
#include <hip/hip_runtime.h>

#define NB 2
#define CIN 256
#define HH 64
#define WW 64
#define CCMP 64
#define HO 128
#define WO 128

// ---------------- k1: 1x1 conv x(2,256,64,64) -> comp(2,64,64,64) ----------------
__global__ void k1_comp(const float* __restrict__ x, const float* __restrict__ wc,
                        const float* __restrict__ bc, float* __restrict__ comp) {
  int b = blockIdx.x;          // 256 blocks: n(2) * ccg(8) * hq(16)
  int n = b >> 7;
  int ccg = (b >> 4) & 7;
  int hq = b & 15;
  int hsub = threadIdx.x >> 6;
  int w = threadIdx.x & 63;
  int h = hq * 4 + hsub;
  float acc[8];
#pragma unroll
  for (int j = 0; j < 8; ++j) acc[j] = bc[ccg * 8 + j];
  const float* xp = x + ((size_t)(n * CIN) * HH + h) * WW + w;
#pragma unroll 4
  for (int c = 0; c < CIN; ++c) {
    float xv = xp[(size_t)c * HH * WW];
#pragma unroll
    for (int j = 0; j < 8; ++j) acc[j] += xv * wc[(ccg * 8 + j) * CIN + c];
  }
#pragma unroll
  for (int j = 0; j < 8; ++j)
    comp[((size_t)(n * CCMP + ccg * 8 + j) * HH + h) * WW + w] = acc[j];
}

// ------------- k2: fused 3x3 convs comp -> off(8ch) + ker(25ch), pad 1 -------------
__global__ void k2_conv3(const float* __restrict__ comp,
                         const float* __restrict__ w_off, const float* __restrict__ b_off,
                         const float* __restrict__ w_ker, const float* __restrict__ b_ker,
                         float* __restrict__ offb, float* __restrict__ kerb) {
  int b = blockIdx.x;           // 352 blocks: n(2) * ocg(11) * hq(16)
  int n = b / 176;
  int r = b % 176;
  int ocg = r / 16;
  int hq = r % 16;
  int hsub = threadIdx.x >> 6;
  int w = threadIdx.x & 63;
  int h = hq * 4 + hsub;
  float acc[3];
#pragma unroll
  for (int j = 0; j < 3; ++j) {
    int oc = ocg * 3 + j;
    acc[j] = (oc < 8) ? b_off[oc] : b_ker[oc - 8];
  }
  for (int c = 0; c < CCMP; ++c) {
    const float* cp = comp + (size_t)(n * CCMP + c) * HH * WW;
    float t[9];
#pragma unroll
    for (int dy = 0; dy < 3; ++dy) {
      int rr = h + dy - 1;
#pragma unroll
      for (int dx = 0; dx < 3; ++dx) {
        int cc = w + dx - 1;
        bool ok = (rr >= 0) && (rr < HH) && (cc >= 0) && (cc < WW);
        t[dy * 3 + dx] = ok ? cp[rr * WW + cc] : 0.f;
      }
    }
#pragma unroll
    for (int j = 0; j < 3; ++j) {
      int oc = ocg * 3 + j;
      const float* wp = (oc < 8) ? (w_off + (size_t)(oc * CCMP + c) * 9)
                                 : (w_ker + (size_t)((oc - 8) * CCMP + c) * 9);
#pragma unroll
      for (int t9 = 0; t9 < 9; ++t9) acc[j] += t[t9] * wp[t9];
    }
  }
#pragma unroll
  for (int j = 0; j < 3; ++j) {
    int oc = ocg * 3 + j;
    if (oc < 8) offb[((size_t)(n * 8 + oc) * HH + h) * WW + w] = acc[j];
    else        kerb[((size_t)(n * 25 + (oc - 8)) * HH + h) * WW + w] = acc[j];
  }
}

// ---------------- k3: softmax over the 25 ker channels, in place ----------------
__global__ void k3_softmax(float* __restrict__ kerb) {
  int t = blockIdx.x * 256 + threadIdx.x;  // 8192 threads
  int n = t >> 12;
  int pos = t & 4095;
  float v[25];
  float mx = -1e30f;
#pragma unroll
  for (int k = 0; k < 25; ++k) {
    v[k] = kerb[(size_t)(n * 25 + k) * 4096 + pos];
    mx = fmaxf(mx, v[k]);
  }
  float s = 0.f;
#pragma unroll
  for (int k = 0; k < 25; ++k) { v[k] = expf(v[k] - mx); s += v[k]; }
  float inv = 1.f / s;
#pragma unroll
  for (int k = 0; k < 25; ++k) kerb[(size_t)(n * 25 + k) * 4096 + pos] = v[k] * inv;
}

// ------- k4: bilinear-sample mask at offset positions -> wts(n,h,w,[pq],[k]) -------
__global__ void k4_wts(const float* __restrict__ offb, const float* __restrict__ mask,
                       float* __restrict__ wts) {
  int t = blockIdx.x * 256 + threadIdx.x;   // 32768 threads: (n, ho, wo)
  int n = t >> 14;
  int r = t & 16383;
  int ho = r >> 7;
  int wo = r & 127;
  int h = ho >> 1, p = ho & 1, w = wo >> 1, q = wo & 1;
  int pq = p * 2 + q;
  float offx = offb[((size_t)(n * 8 + pq) * HH + h) * WW + w];
  float offy = offb[((size_t)(n * 8 + 4 + pq) * HH + h) * WW + w];
  // align_corners=True + border clamp algebra reduces to sampling at (h+offy, w+offx)
  float ix = fminf(fmaxf((float)w + offx, 0.f), 63.f);
  float iy = fminf(fmaxf((float)h + offy, 0.f), 63.f);
  float x0f = floorf(ix), y0f = floorf(iy);
  float fx = ix - x0f, fy = iy - y0f;
  int x0 = (int)x0f, y0 = (int)y0f;
  int x1 = min(x0 + 1, 63), y1 = min(y0 + 1, 63);
  float w00 = (1.f - fx) * (1.f - fy), w01 = fx * (1.f - fy);
  float w10 = (1.f - fx) * fy,         w11 = fx * fy;
  float* wp = wts + ((((size_t)n * HH + h) * WW + w) * 4 + pq) * 25;
#pragma unroll
  for (int k = 0; k < 25; ++k) {
    const float* mp = mask + (size_t)(n * 25 + k) * 4096;
    wp[k] = mp[y0 * 64 + x0] * w00 + mp[y0 * 64 + x1] * w01 +
            mp[y1 * 64 + x0] * w10 + mp[y1 * 64 + x1] * w11;
  }
}

// -------- k5: out[n,c,2h+p,2w+q] = sum_k wt[n,h,w,pq,k] * x[n,c,h+ki-2,w+kj-2] --------
// lane = w (coalesced). Two half-passes (pq rows) with only 50 weights live -> no spill.
__global__ __launch_bounds__(256) void k5_out(const float* __restrict__ x,
                                              const float* __restrict__ wts,
                                              float* __restrict__ out) {
  int b = blockIdx.x;       // 1024 blocks: n(2) * h(64) * cg(8)
  int n = b >> 9;
  int r = b & 511;
  int h = r >> 3;
  int cg = r & 7;
  int wave = threadIdx.x >> 6;
  int w = threadIdx.x & 63;
  const float* wrow = wts + (((size_t)n * HH + h) * WW + w) * 100;
  int c0 = cg * 32 + wave * 8;   // 8 channels per wave

#pragma unroll
  for (int half = 0; half < 2; ++half) {
    // hoist 50 weights (pq = 2*half, 2*half+1) via 8B-aligned float2 loads
    float wt[50];
    const float2* wp2 = (const float2*)(wrow + half * 50);
#pragma unroll
    for (int i = 0; i < 25; ++i) {
      float2 v = wp2[i];
      wt[2 * i] = v.x; wt[2 * i + 1] = v.y;
    }
    for (int ci = 0; ci < 8; ++ci) {
      int c = c0 + ci;
      const float* xc = x + (size_t)(n * CIN + c) * HH * WW;
      float a0 = 0.f, a1 = 0.f;
#pragma unroll
      for (int dy = 0; dy < 5; ++dy) {
        int rr = h + dy - 2;
        bool rok = (unsigned)rr < (unsigned)HH;
        const float* xr = xc + rr * WW;
#pragma unroll
        for (int dx = 0; dx < 5; ++dx) {
          int cc = w + dx - 2;
          float xv = (rok && (unsigned)cc < (unsigned)WW) ? xr[cc] : 0.f;
          int k = dy * 5 + dx;
          a0 += wt[k] * xv;
          a1 += wt[25 + k] * xv;
        }
      }
      float2* o = (float2*)(out + ((size_t)(n * CIN + c) * HO + 2 * h + half) * WO + 2 * w);
      *o = make_float2(a0, a1);
    }
  }
}

extern "C" void kernel_launch(void* const* d_in, const int* in_sizes, int n_in,
                              void* d_out, int out_size, void* d_ws, size_t ws_size,
                              hipStream_t stream) {
  const float* x      = (const float*)d_in[0];
  const float* w_comp = (const float*)d_in[1];
  const float* b_comp = (const float*)d_in[2];
  const float* w_off  = (const float*)d_in[3];
  const float* b_off  = (const float*)d_in[4];
  const float* w_ker  = (const float*)d_in[5];
  const float* b_ker  = (const float*)d_in[6];
  float* out = (float*)d_out;

  float* ws   = (float*)d_ws;
  float* comp = ws;                       // 2*64*64*64   = 524288 floats
  float* offb = comp + 524288;            // 2*8*64*64    = 65536
  float* kerb = offb + 65536;             // 2*25*64*64   = 204800 (softmax in place)
  float* wts  = kerb + 204800;            // 2*64*64*100  = 819200 (16B-aligned)

  k1_comp<<<256, 256, 0, stream>>>(x, w_comp, b_comp, comp);
  k2_conv3<<<352, 256, 0, stream>>>(comp, w_off, b_off, w_ker, b_ker, offb, kerb);
  k3_softmax<<<32, 256, 0, stream>>>(kerb);
  k4_wts<<<128, 256, 0, stream>>>(offb, kerb, wts);
  k5_out<<<1024, 256, 0, stream>>>(x, wts, out);
}